// Round 2
// baseline (1442.063 us; speedup 1.0000x reference)
//
#include <hip/hip_runtime.h>
#include <math.h>
#include <stdint.h>

namespace {

constexpr int T = 50;
constexpr int NB = 32768;
constexpr int H = 128;
constexpr int NTHREADS = 256;   // 4 waves
constexpr int BLK_ROWS = 128;   // 4 waves x 32 rows

typedef float v4f __attribute__((ext_vector_type(4)));
typedef float v2f __attribute__((ext_vector_type(2)));
typedef short short8 __attribute__((ext_vector_type(8)));

union FU { float f; uint32_t u; };
union U8 { uint32_t u[4]; short8 v; };

__device__ __forceinline__ uint32_t pack_hi16(uint32_t odd, uint32_t even) {
  return (odd & 0xFFFF0000u) | (even >> 16);
}

// Exact 3-way bf16 split of an fp32 value (truncated 8-bit significand chunks).
// a == bf16(hi) + bf16(mid) + bf16(lo) exactly (24 = 8+8+8 mantissa bits).
__device__ __forceinline__ void split3(float a, uint32_t& hi, uint32_t& mid, uint32_t& lo) {
  FU c0; c0.f = a;
  uint32_t uh = c0.u & 0xFFFF0000u;
  FU fh; fh.u = uh;
  float r1 = a - fh.f;              // exact
  FU c1; c1.f = r1;
  uint32_t um = c1.u & 0xFFFF0000u;
  FU fm; fm.u = um;
  float r2 = r1 - fm.f;             // exact; r2 has <=8 significand bits
  FU c2; c2.f = r2;                 // low 16 bits of c2.u are zero
  hi = uh; mid = um; lo = c2.u;
}

__device__ __forceinline__ v4f mfma16(short8 a, short8 b, v4f c) {
  return __builtin_amdgcn_mfma_f32_16x16x32_bf16(a, b, c, 0, 0, 0);
}

__global__ __launch_bounds__(NTHREADS, 1)
void fwdsim_mfma(const float* __restrict__ proj,   // (B, 64)
                 const float* __restrict__ idm,    // (B, T, 12)
                 const float* __restrict__ merg,   // (B, T, 3)
                 const float* __restrict__ W1,     // (73, 128)
                 const float* __restrict__ b1,     // (128)
                 const float* __restrict__ W2,     // (128, 128)
                 const float* __restrict__ b2,     // (128)
                 const float* __restrict__ W3,     // (128, 1)
                 const float* __restrict__ b3,     // (1)
                 const float* __restrict__ smean,  // (6)
                 const float* __restrict__ svar,   // (6)
                 float* __restrict__ out)          // (B, T)
{
  // 98304 B: W2 as 3 bf16 split planes, fragment-ordered [kt*8+nt][split][lane]
  __shared__ short8 sB[3 * 4 * 8 * 64];
  // 65536 B: per-wave h1 buffer [wave][row(32)][col(128)] fp32
  __shared__ float sH[4 * 32 * H];
  // total = 163840 B (exactly 160 KiB)

  const int tid  = threadIdx.x;
  const int wave = tid >> 6;
  const int lane = tid & 63;
  const int g    = lane >> 4;   // 0..3 (row quarter in MFMA C layout)
  const int o    = lane & 15;   // 0..15 (column within N-tile)

  // ---- prologue A: W2 -> 3 exact bf16 split planes, frag-ordered in LDS ----
  // B-frag for 16x16x32: lane L holds B[k = kt*32 + (L>>4)*8 + j][n = nt*16 + (L&15)]
  for (int job = tid; job < 2048; job += NTHREADS) {
    const int lj   = job & 63;
    const int ktnt = job >> 6;          // kt*8 + nt
    const int k0   = (ktnt >> 3) * 32 + (lj >> 4) * 8;
    const int n    = (ktnt & 7) * 16 + (lj & 15);
    uint32_t hi[8], mi[8], lo[8];
#pragma unroll
    for (int j = 0; j < 8; ++j) {
      split3(W2[(k0 + j) * H + n], hi[j], mi[j], lo[j]);
    }
    U8 fh, fm, fl;
#pragma unroll
    for (int d = 0; d < 4; ++d) {
      fh.u[d] = pack_hi16(hi[2*d+1], hi[2*d]);
      fm.u[d] = pack_hi16(mi[2*d+1], mi[2*d]);
      fl.u[d] = pack_hi16(lo[2*d+1], lo[2*d]);
    }
    const int base = ktnt * 192 + lj;
    sB[base      ] = fh.v;
    sB[base +  64] = fm.v;
    sB[base + 128] = fl.v;
  }

  // ---- per-lane constants ----
  const int wave_row0 = blockIdx.x * BLK_ROWS + wave * 32;
  int mloc[8];   // the 8 local rows this lane owns for state/env/layer1
#pragma unroll
  for (int rr = 0; rr < 8; ++rr)
    mloc[rr] = (rr < 4) ? (4*g + rr) : (16 + 4*g + (rr - 4));

  float mean[6], istd[6];
#pragma unroll
  for (int c = 0; c < 6; ++c) { mean[c] = smean[c]; istd[c] = 1.0f / sqrtf(svar[c]); }
  const float b3v = b3[0];
  float b2r[8], W3r[8];
#pragma unroll
  for (int nt = 0; nt < 8; ++nt) { b2r[nt] = b2[nt*16 + o]; W3r[nt] = W3[nt*16 + o]; }

  // W1 env rows (64..72), this lane's 8 columns
  v4f w1e[9][2];
#pragma unroll
  for (int k = 0; k < 9; ++k) {
    const float* wp = W1 + (64 + k) * H + 8 * o;
    w1e[k][0] = *(const v4f*)(wp);
    w1e[k][1] = *(const v4f*)(wp + 4);
  }

  // base1 = b1 + proj @ W1[0:64] for this lane's 8 rows x 8 cols (time-invariant)
  v4f baseq[8][2];
#pragma unroll
  for (int rr = 0; rr < 8; ++rr) {
    baseq[rr][0] = *(const v4f*)(b1 + 8*o);
    baseq[rr][1] = *(const v4f*)(b1 + 8*o + 4);
  }
  for (int k4 = 0; k4 < 16; ++k4) {
    v4f w0[4], w1v[4];
#pragma unroll
    for (int kk = 0; kk < 4; ++kk) {
      const float* wp = W1 + (k4*4 + kk) * H + 8*o;
      w0[kk]  = *(const v4f*)(wp);
      w1v[kk] = *(const v4f*)(wp + 4);
    }
#pragma unroll
    for (int rr = 0; rr < 8; ++rr) {
      v4f p = *(const v4f*)(proj + (size_t)(wave_row0 + mloc[rr]) * 64 + k4*4);
#pragma unroll
      for (int kk = 0; kk < 4; ++kk) {
        baseq[rr][0] += p[kk] * w0[kk];
        baseq[rr][1] += p[kk] * w1v[kk];
      }
    }
  }
  __syncthreads();  // sB ready; no further barriers (sB read-only, sH wave-private)

  // ---- recurrent state ----
  float ego_v[8], ego_x[8], act[8];
  v4f  sa[8];  v2f fb[8];  float exr[8], mc0[8], mc1[8], mc2[8];

  auto issue_loads = [&](int t) {
#pragma unroll
    for (int rr = 0; rr < 8; ++rr) {
      const int row = wave_row0 + mloc[rr];
      const float* ip = idm + (size_t)row * (T * 12) + t * 12;
      sa[rr]  = *(const v4f*)(ip);        // s0..s3
      fb[rr]  = *(const v2f*)(ip + 4);    // s4 (f_glob_x), s5 (m_glob_x)
      exr[rr] = ip[11];                   // s11 (m_veh_exists)
      const float* mp = merg + (size_t)row * (T * 3) + t * 3;
      mc0[rr] = mp[0]; mc1[rr] = mp[1]; mc2[rr] = mp[2];
    }
  };
  issue_loads(0);

#pragma unroll 1
  for (int t = 0; t < T; ++t) {
    // ---- state update + env + layer 1 (fp32), write h rows to wave-private LDS ----
#pragma unroll
    for (int rr = 0; rr < 8; ++rr) {
      const float s0 = sa[rr][0], fv = sa[rr][1], mv = sa[rr][2], s3 = sa[rr][3];
      const float fgx = fb[rr][0], mgx = fb[rr][1];
      const float ex = exr[rr];
      if (t == 0) { ego_v[rr] = s0; ego_x[rr] = s3; }
      else {
        ego_v[rr] += act[rr] * 0.1f;
        ego_x[rr] += ego_v[rr] * 0.1f + act[rr] * 0.005f;
      }
      float xk[9];
      xk[0] = (ego_v[rr]                                    - mean[0]) * istd[0];
      xk[1] = (fv                                           - mean[1]) * istd[1];
      xk[2] = (ego_v[rr] - fv                               - mean[2]) * istd[2];
      xk[3] = (fgx - ego_x[rr]                              - mean[3]) * istd[3];
      xk[4] = ((ego_v[rr] - mv) * ex                        - mean[4]) * istd[4];
      xk[5] = ((mgx - ego_x[rr]) * ex + (1.0f - ex) * 100.0f - mean[5]) * istd[5];
      xk[6] = mc0[rr]; xk[7] = mc1[rr]; xk[8] = mc2[rr];

      v4f h0 = baseq[rr][0], h1 = baseq[rr][1];
#pragma unroll
      for (int k = 0; k < 9; ++k) { h0 += xk[k] * w1e[k][0]; h1 += xk[k] * w1e[k][1]; }
#pragma unroll
      for (int e = 0; e < 4; ++e) { h0[e] = fmaxf(h0[e], 0.f); h1[e] = fmaxf(h1[e], 0.f); }
      v4f* dst = (v4f*)&sH[wave * 4096 + mloc[rr] * 128 + 8 * o];
      dst[0] = h0; dst[1] = h1;
    }
    if (t + 1 < T) issue_loads(t + 1);   // prefetch next step's inputs over MFMA phase

    // ---- layer 2: h2 = relu(h1 @ W2 + b2) via 6-term exact-split bf16 MFMA ----
    v4f acc[2][8];
#pragma unroll
    for (int mt = 0; mt < 2; ++mt)
#pragma unroll
      for (int nt = 0; nt < 8; ++nt)
        acc[mt][nt] = (v4f){b2r[nt], b2r[nt], b2r[nt], b2r[nt]};

#pragma unroll
    for (int kt = 0; kt < 4; ++kt) {
      // A-frags for both 16-row M-tiles: lane holds h[m = mt*16 + (lane&15)][k0..k0+7]
      short8 ah[2], am[2], al[2];
#pragma unroll
      for (int mt = 0; mt < 2; ++mt) {
        const int mrow = mt * 16 + (lane & 15);
        const float* src = &sH[wave * 4096 + mrow * 128 + kt * 32 + g * 8];
        v4f f0 = ((const v4f*)src)[0];
        v4f f1 = ((const v4f*)src)[1];
        uint32_t hi[8], mi[8], lo[8];
#pragma unroll
        for (int e = 0; e < 4; ++e) split3(f0[e], hi[e],   mi[e],   lo[e]);
#pragma unroll
        for (int e = 0; e < 4; ++e) split3(f1[e], hi[4+e], mi[4+e], lo[4+e]);
        U8 uh, um, ul;
#pragma unroll
        for (int d = 0; d < 4; ++d) {
          uh.u[d] = pack_hi16(hi[2*d+1], hi[2*d]);
          um.u[d] = pack_hi16(mi[2*d+1], mi[2*d]);
          ul.u[d] = pack_hi16(lo[2*d+1], lo[2*d]);
        }
        ah[mt] = uh.v; am[mt] = um.v; al[mt] = ul.v;
      }
#pragma unroll
      for (int nt = 0; nt < 8; ++nt) {
        const int bb = (kt * 8 + nt) * 192 + lane;
        short8 bh = sB[bb], bm = sB[bb + 64], bl = sB[bb + 128];
#pragma unroll
        for (int mt = 0; mt < 2; ++mt) {
          // smallest terms first for accumulation accuracy
          acc[mt][nt] = mfma16(ah[mt], bl, acc[mt][nt]);  // a0*b2  (~2^-18)
          acc[mt][nt] = mfma16(al[mt], bh, acc[mt][nt]);  // a2*b0  (~2^-18)
          acc[mt][nt] = mfma16(am[mt], bm, acc[mt][nt]);  // a1*b1  (~2^-18)
          acc[mt][nt] = mfma16(ah[mt], bm, acc[mt][nt]);  // a0*b1  (~2^-9)
          acc[mt][nt] = mfma16(am[mt], bh, acc[mt][nt]);  // a1*b0  (~2^-9)
          acc[mt][nt] = mfma16(ah[mt], bh, acc[mt][nt]);  // a0*b0  (1)
        }
      }
    }

    // ---- layer 3: act = relu(h2) @ W3 + b3; butterfly over the 16-lane col group ----
    float part[8];
#pragma unroll
    for (int mt = 0; mt < 2; ++mt)
#pragma unroll
      for (int r = 0; r < 4; ++r) {
        float p = 0.f;
#pragma unroll
        for (int nt = 0; nt < 8; ++nt) p += fmaxf(acc[mt][nt][r], 0.f) * W3r[nt];
        part[mt * 4 + r] = p;
      }
#pragma unroll
    for (int m = 1; m <= 8; m <<= 1) {
#pragma unroll
      for (int rr = 0; rr < 8; ++rr) part[rr] += __shfl_xor(part[rr], m, 64);
    }
#pragma unroll
    for (int rr = 0; rr < 8; ++rr) act[rr] = part[rr] + b3v;
    // C-layout rows 4g+reg match mloc[] exactly, so act[rr] pairs with state rr.

    if (o < 4) {
      out[(size_t)(wave_row0 + mloc[o    ]) * T + t] = act[o    ];
      out[(size_t)(wave_row0 + mloc[o + 4]) * T + t] = act[o + 4];
    }
  }
}

}  // namespace

extern "C" void kernel_launch(void* const* d_in, const int* in_sizes, int n_in,
                              void* d_out, int out_size, void* d_ws, size_t ws_size,
                              hipStream_t stream) {
  const float* proj  = (const float*)d_in[0];
  const float* idm   = (const float*)d_in[1];
  const float* merg  = (const float*)d_in[2];
  const float* W1    = (const float*)d_in[3];
  const float* b1    = (const float*)d_in[4];
  const float* W2    = (const float*)d_in[5];
  const float* b2    = (const float*)d_in[6];
  const float* W3    = (const float*)d_in[7];
  const float* b3    = (const float*)d_in[8];
  const float* smean = (const float*)d_in[9];
  const float* svar  = (const float*)d_in[10];
  // d_in[11] = rollout_len (always 50 here)

  dim3 grid(NB / BLK_ROWS);   // 256 blocks -> 1 per CU, single pass
  dim3 block(NTHREADS);       // 256 threads = 4 waves x 32 rows
  hipLaunchKernelGGL(fwdsim_mfma, grid, block, 0, stream,
                     proj, idm, merg, W1, b1, W2, b2, W3, b3, smean, svar,
                     (float*)d_out);
}